// Round 10
// baseline (2408.426 us; speedup 1.0000x reference)
//
#include <hip/hip_runtime.h>
#include <cstdint>

#define BSZ   64
#define MAXQ  32
#define DH    300
#define N_ENT 100000
#define N_REL 18
#define N_TRI 600000
#define D_CLS 1024

// e_s [64][N_ENT] -> e_t [N_ENT][64]
__global__ __launch_bounds__(256) void k_transpose(const float* __restrict__ e_s,
                                                   float* __restrict__ e_t) {
  __shared__ float T[64][65];
  int e0 = blockIdx.x * 64;
  int lane = threadIdx.x & 63;
  int w = threadIdx.x >> 6;
  for (int b = w; b < 64; b += 4) {
    int e = e0 + lane;
    T[b][lane] = (e < N_ENT) ? e_s[b * N_ENT + e] : 0.f;
  }
  __syncthreads();
  for (int i = w; i < 64; i += 4) {
    int e = e0 + i;
    if (e < N_ENT) e_t[e * 64 + lane] = T[lane][i];
  }
}

// ---------- CSR-by-obj build (triples are launch-invariant; built once) ----------
__global__ __launch_bounds__(256) void k_hist(const int* __restrict__ obj,
                                              int* __restrict__ cnt) {
  int stride = gridDim.x * 256;
  for (int i = blockIdx.x * 256 + threadIdx.x; i < N_TRI; i += stride)
    atomicAdd(&cnt[obj[i]], 1);
}

// Per-block exclusive scan of cnt -> cursor(local), block totals -> blockSums
__global__ __launch_bounds__(256) void k_scan1(const int* __restrict__ cnt,
                                               int* __restrict__ cursor,
                                               int* __restrict__ blockSums) {
  __shared__ int sdata[256];
  int i = blockIdx.x * 256 + threadIdx.x;
  int v = (i < N_ENT) ? cnt[i] : 0;
  sdata[threadIdx.x] = v;
  __syncthreads();
  for (int off = 1; off < 256; off <<= 1) {
    int t = (threadIdx.x >= off) ? sdata[threadIdx.x - off] : 0;
    __syncthreads();
    sdata[threadIdx.x] += t;
    __syncthreads();
  }
  if (i < N_ENT) cursor[i] = sdata[threadIdx.x] - v;  // exclusive local scan
  if (threadIdx.x == 255) blockSums[blockIdx.x] = sdata[255];
}

// Add block offsets -> rowStart + cursor (scatter cursors)
__global__ __launch_bounds__(256) void k_scan2(const int* __restrict__ blockSums,
                                               int* __restrict__ rowStart,
                                               int* __restrict__ cursor) {
  __shared__ int offs;
  int b = blockIdx.x;
  if (threadIdx.x == 0) {
    int o = 0;
    for (int j = 0; j < b; j++) o += blockSums[j];
    offs = o;
  }
  __syncthreads();
  int i = b * 256 + threadIdx.x;
  if (i < N_ENT) {
    int v = cursor[i] + offs;
    rowStart[i] = v;
    cursor[i] = v;
  }
  if (i == 0) rowStart[N_ENT] = N_TRI;
}

// packed[pos] = subj | (rel << 17)   (subj < 2^17, rel < 32)
__global__ __launch_bounds__(256) void k_scatter(const int* __restrict__ subj,
                                                 const int* __restrict__ rel,
                                                 const int* __restrict__ obj,
                                                 int* __restrict__ cursor,
                                                 uint32_t* __restrict__ packed) {
  int stride = gridDim.x * 256;
  for (int i = blockIdx.x * 256 + threadIdx.x; i < N_TRI; i += stride) {
    int o = obj[i];
    int pos = atomicAdd(&cursor[o], 1);
    packed[pos] = (uint32_t)subj[i] | ((uint32_t)rel[i] << 17);
  }
}

// Fused per-step controller: q_t, cq_t, word attention softmax, last_c, rel_dist.
__global__ __launch_bounds__(320) void k_step(
    const float* __restrict__ qwh, const float* __restrict__ qemb,
    const float* __restrict__ Wstep, const float* __restrict__ bstep,
    const float* __restrict__ Wcq, const float* __restrict__ bcq,
    const float* __restrict__ Wca, const float* __restrict__ bca,
    const float* __restrict__ Wrel, const float* __restrict__ brel,
    float* __restrict__ last_c, float* __restrict__ rel_dist, int t) {
  int b = blockIdx.x;
  int tid = threadIdx.x;
  __shared__ float qe[DH], qtL[DH], lcL[DH], wcq[DH];
  __shared__ float lg[MAXQ], red[MAXQ * 8], dist[MAXQ];
  __shared__ float relL[N_REL];
  __shared__ float mx, sm;

  for (int j = tid; j < DH; j += 320) {
    qe[j] = qemb[b * DH + j];
    lcL[j] = last_c[b * DH + j];
  }
  __syncthreads();

  const float* Wt = Wstep + t * DH * DH;
  for (int j = tid; j < DH; j += 320) {
    float acc = bstep[t * DH + j];
    for (int k = 0; k < DH; k++) acc += qe[k] * Wt[k * DH + j];
    qtL[j] = tanhf(acc);
  }
  __syncthreads();

  for (int j = tid; j < DH; j += 320) {
    float acc = bcq[j];
    for (int k = 0; k < DH; k++) acc += lcL[k] * Wcq[k * DH + j];
    for (int k = 0; k < DH; k++) acc += qtL[k] * Wcq[(DH + k) * DH + j];
    wcq[j] = acc * Wca[j];
  }
  __syncthreads();

  if (tid < MAXQ * 8) {
    int q = tid >> 3, sub = tid & 7;
    const float* row = qwh + (b * MAXQ + q) * DH;
    float acc = 0.f;
    for (int d = sub; d < DH; d += 8) acc += wcq[d] * row[d];
    red[tid] = acc;
  }
  __syncthreads();
  if (tid < MAXQ) {
    float acc = bca[0];
    for (int s = 0; s < 8; s++) acc += red[tid * 8 + s];
    lg[tid] = acc;
  }
  __syncthreads();
  if (tid == 0) {
    float m = lg[0];
    for (int q = 1; q < MAXQ; q++) m = fmaxf(m, lg[q]);
    mx = m;
  }
  __syncthreads();
  if (tid < MAXQ) dist[tid] = expf(lg[tid] - mx);
  __syncthreads();
  if (tid == 0) {
    float s = 0.f;
    for (int q = 0; q < MAXQ; q++) s += dist[q];
    sm = s;
  }
  __syncthreads();

  for (int j = tid; j < DH; j += 320) {
    float acc = 0.f;
    for (int q = 0; q < MAXQ; q++) acc += dist[q] * qwh[(b * MAXQ + q) * DH + j];
    acc /= sm;
    lcL[j] = acc;
    last_c[b * DH + j] = acc;
  }
  __syncthreads();

  if (tid < N_REL) {
    float acc = brel[tid];
    for (int d = 0; d < DH; d++) acc += lcL[d] * Wrel[d * N_REL + tid];
    relL[tid] = acc;
  }
  __syncthreads();
  if (tid == 0) {
    float m = relL[0];
    for (int r = 1; r < N_REL; r++) m = fmaxf(m, relL[r]);
    mx = m;
  }
  __syncthreads();
  if (tid < N_REL) relL[tid] = expf(relL[tid] - mx);
  __syncthreads();
  if (tid == 0) {
    float s = 0.f;
    for (int r = 0; r < N_REL; r++) s += relL[r];
    sm = s;
  }
  __syncthreads();
  if (tid < N_REL) rel_dist[b * N_REL + tid] = relL[tid] / sm;
}

// follow (CSR, atomic-free): one wave per output entity, grid-stride.
// e_out[o*64+lane] = sum over row(o) of e_in[subj*64+lane] * relL[lane][rel]
// relL padded to stride 19 (gcd(19,32)=1 -> conflict-free LDS reads).
// Inner loop hand-unrolled x4: batch the independent gathers before the FMAs.
__global__ __launch_bounds__(256) void k_follow(
    const float* __restrict__ e_in, const float* __restrict__ rel_dist,
    const int* __restrict__ rowStart, const uint32_t* __restrict__ packed,
    float* __restrict__ e_out, float* __restrict__ sums) {
  __shared__ float relL[BSZ * 19];
  for (int i = threadIdx.x; i < BSZ * N_REL; i += 256) {
    int l = i / N_REL, r = i - l * N_REL;
    relL[l * 19 + r] = rel_dist[i];
  }
  __syncthreads();
  int lane = threadIdx.x & 63;
  int wave = (blockIdx.x << 2) | (threadIdx.x >> 6);
  int nwaves = gridDim.x << 2;
  const float* myrel = relL + lane * 19;
  float sacc = 0.f;
  for (int o = wave; o < N_ENT; o += nwaves) {
    int beg = rowStart[o], end = rowStart[o + 1];
    float acc = 0.f;
    int t = beg;
    for (; t + 4 <= end; t += 4) {
      uint32_t p0 = packed[t + 0];
      uint32_t p1 = packed[t + 1];
      uint32_t p2 = packed[t + 2];
      uint32_t p3 = packed[t + 3];
      float v0 = e_in[(p0 & 0x1FFFF) * 64 + lane];
      float v1 = e_in[(p1 & 0x1FFFF) * 64 + lane];
      float v2 = e_in[(p2 & 0x1FFFF) * 64 + lane];
      float v3 = e_in[(p3 & 0x1FFFF) * 64 + lane];
      acc += v0 * myrel[p0 >> 17];
      acc += v1 * myrel[p1 >> 17];
      acc += v2 * myrel[p2 >> 17];
      acc += v3 * myrel[p3 >> 17];
    }
    for (; t < end; ++t) {
      uint32_t p = packed[t];
      acc += e_in[(p & 0x1FFFF) * 64 + lane] * myrel[p >> 17];
    }
    e_out[(size_t)o * 64 + lane] = acc;
    sacc += acc;
  }
  if (sums) atomicAdd(&sums[lane], sacc);
}

#define PF_NB 512
#define PF_EPB 196
#define PF_CH 32
#define PF_RS 304   // padded row stride (floats), 76 float4
__global__ __launch_bounds__(256) void k_predfeat(
    const float* __restrict__ e, const float* __restrict__ sums,
    const float* __restrict__ ent_emb, float* __restrict__ partials) {
  __shared__ float embL[PF_CH * PF_RS];
  __shared__ float eL[PF_CH * 64];
  int tid = threadIdx.x;
  int b = tid & 63, g = tid >> 6;
  int e0 = blockIdx.x * PF_EPB;
  int e1 = e0 + PF_EPB;
  if (e1 > N_ENT) e1 = N_ENT;

  int sb = (4 * tid) & 63;
  float4 inv4 = make_float4(1.f / (sums[sb + 0] + 1e-6f), 1.f / (sums[sb + 1] + 1e-6f),
                            1.f / (sums[sb + 2] + 1e-6f), 1.f / (sums[sb + 3] + 1e-6f));

  float4 acc[19];
  #pragma unroll
  for (int k = 0; k < 19; k++) acc[k] = make_float4(0.f, 0.f, 0.f, 0.f);

  float4* embL4 = (float4*)embL;
  float4* eL4 = (float4*)eL;

  for (int ecur = e0; ecur < e1; ecur += PF_CH) {
    int n = min(PF_CH, e1 - ecur);
    __syncthreads();
    const float4* src = (const float4*)(ent_emb + (size_t)ecur * DH);
    for (int i = tid; i < n * 75; i += 256) {
      int ee = i / 75, j = i - ee * 75;
      embL4[ee * 76 + j] = src[i];
      if (j == 0) embL4[ee * 76 + 75] = make_float4(0.f, 0.f, 0.f, 0.f);
    }
    const float4* esrc = (const float4*)(e + (size_t)ecur * 64);
    for (int i = tid; i < n * 16; i += 256) {
      float4 v = esrc[i];
      v.x *= inv4.x; v.y *= inv4.y; v.z *= inv4.z; v.w *= inv4.w;
      eL4[i] = v;
    }
    __syncthreads();
    for (int ee = 0; ee < n; ee++) {
      float ev = eL[ee * 64 + b];
      const float4* em = embL4 + ee * 76 + g * 19;
      #pragma unroll
      for (int k = 0; k < 19; k++) {
        float4 m = em[k];
        acc[k].x += ev * m.x;
        acc[k].y += ev * m.y;
        acc[k].z += ev * m.z;
        acc[k].w += ev * m.w;
      }
    }
  }

  float* pout = partials + (size_t)blockIdx.x * (PF_RS * 64);
  #pragma unroll
  for (int k = 0; k < 19; k++) {
    int d = g * 76 + k * 4;
    pout[(d + 0) * 64 + b] = acc[k].x;
    pout[(d + 1) * 64 + b] = acc[k].y;
    pout[(d + 2) * 64 + b] = acc[k].z;
    pout[(d + 3) * 64 + b] = acc[k].w;
  }
}

__global__ __launch_bounds__(256) void k_reduce_pf(const float* __restrict__ partials,
                                                   float* __restrict__ pf) {
  int j = blockIdx.x * 256 + threadIdx.x;
  if (j >= DH * 64) return;
  int d = j >> 6, b = j & 63;
  float acc = 0.f;
  for (int c = 0; c < PF_NB; c++) acc += partials[(size_t)c * (PF_RS * 64) + j];
  pf[b * DH + d] = acc;
}

// hiddenT[j][b] = relu(pf[b,:] @ We1[:,j] + be1[j])
__global__ __launch_bounds__(256) void k_hidden(const float* __restrict__ pf,
                                                const float* __restrict__ We1,
                                                const float* __restrict__ be1,
                                                float* __restrict__ hiddenT) {
  int idx = blockIdx.x * 256 + threadIdx.x;
  int j = idx & (D_CLS - 1);
  int b = idx >> 10;
  float acc = be1[j];
  const float* p = pf + b * DH;
  for (int k = 0; k < DH; k++) acc += p[k] * We1[k * D_CLS + j];
  hiddenT[j * 64 + b] = fmaxf(acc, 0.f);
}

// Final GEMM — We2 read exactly once AND 4x wave-parallelism:
// block = 256 threads (4 waves) covering 64 output columns (lane = column).
// Wave w accumulates k in [w*256, w*256+256) into private acc[64] (registers),
// then reduces across waves via LDS float atomics (ds_add_f32, 16 KB), and each
// wave stores 16 b-rows coalesced. 1563 blocks * 4 waves = 6252 waves
// (~6/SIMD) hides the scalar-broadcast hT load latency that capped v8 at 18%
// occupancy / 35% VALUBusy.
#define KF_WAVES 4
#define KF_KPW (D_CLS / KF_WAVES)   // 256
__global__ __launch_bounds__(256) void k_final(const float* __restrict__ hT,
                                               const float* __restrict__ We2,
                                               const float* __restrict__ be2,
                                               float* __restrict__ out) {
  __shared__ float accS[64][64];    // [b][col] 16 KB
  int tid = threadIdx.x;
  int lane = tid & 63;
  int wv_id = tid >> 6;
  int o = blockIdx.x * 64 + lane;
  bool valid = (o < N_ENT);
  int oc = valid ? o : 0;

  for (int i = tid; i < 64 * 64; i += 256) ((float*)accS)[i] = 0.f;
  __syncthreads();

  float acc[64];
  #pragma unroll
  for (int b = 0; b < 64; b++) acc[b] = 0.f;

  int k0 = wv_id * KF_KPW;
  const float* w = We2 + (size_t)k0 * N_ENT + oc;
  const float* h = hT + k0 * 64;
  for (int kk = 0; kk < KF_KPW; kk += 8) {
    float wvv[8];
    #pragma unroll
    for (int u = 0; u < 8; u++) wvv[u] = w[(size_t)(kk + u) * N_ENT];
    #pragma unroll
    for (int u = 0; u < 8; u++) {
      const float* hk = h + (kk + u) * 64;   // wave-uniform -> s_load broadcast
      #pragma unroll
      for (int b = 0; b < 64; b++) acc[b] += hk[b] * wvv[u];
    }
  }

  #pragma unroll
  for (int b = 0; b < 64; b++) atomicAdd(&accS[b][lane], acc[b]);
  __syncthreads();

  if (valid) {
    float bv = be2[oc];
    for (int b = wv_id * 16; b < wv_id * 16 + 16; b++)
      out[(size_t)b * N_ENT + o] = accS[b][lane] + bv;
  }
}

extern "C" void kernel_launch(void* const* d_in, const int* in_sizes, int n_in,
                              void* d_out, int out_size, void* d_ws, size_t ws_size,
                              hipStream_t stream) {
  const float* qwh   = (const float*)d_in[0];
  const float* qemb  = (const float*)d_in[1];
  const float* e_s   = (const float*)d_in[2];
  const float* Wstep = (const float*)d_in[3];
  const float* bstep = (const float*)d_in[4];
  const float* Wcq   = (const float*)d_in[5];
  const float* bcq   = (const float*)d_in[6];
  const float* Wca   = (const float*)d_in[7];
  const float* bca   = (const float*)d_in[8];
  const float* Wrel  = (const float*)d_in[9];
  const float* brel  = (const float*)d_in[10];
  const float* eemb  = (const float*)d_in[11];
  const float* We1   = (const float*)d_in[12];
  const float* be1   = (const float*)d_in[13];
  const float* We2   = (const float*)d_in[14];
  const float* be2   = (const float*)d_in[15];
  const int* subj    = (const int*)d_in[16];
  const int* rel     = (const int*)d_in[17];
  const int* obj     = (const int*)d_in[18];
  float* out = (float*)d_out;

  float* ws = (float*)d_ws;
  const size_t EB = (size_t)N_ENT * 64;            // 6,400,000 floats
  float* e_a      = ws;                             // ping
  float* e_b      = e_a + EB;                       // pong
  float* partials = e_b + EB;                       // 512*304*64 = 9,961,472
  float* last_c   = partials + (size_t)PF_NB * PF_RS * 64;  // 19,200
  float* sums     = last_c + BSZ * DH;              // 64
  float* rel_d    = sums + 64;                      // 1,152
  float* pf       = rel_d + BSZ * N_REL;            // 19,200
  float* hiddenT  = pf + BSZ * DH;                  // 65,536
  int* cnt        = (int*)(hiddenT + BSZ * D_CLS);  // 100,000
  int* rowStart   = cnt + N_ENT;                    // 100,001
  int* cursor     = rowStart + N_ENT + 1;           // 100,000
  int* blockSums  = cursor + N_ENT;                 // 391 (pad to 400)
  uint32_t* packed = (uint32_t*)(blockSums + 400);  // 600,000
  // total ~23.8M words ~95 MB

  // small zero-init: last_c + sums ; cnt histogram
  hipMemsetAsync(last_c, 0, (size_t)(BSZ * DH + 64) * sizeof(float), stream);
  hipMemsetAsync(cnt, 0, (size_t)N_ENT * sizeof(int), stream);

  k_transpose<<<(N_ENT + 63) / 64, 256, 0, stream>>>(e_s, e_a);

  // Build obj-CSR once (triples are step-invariant)
  k_hist<<<1024, 256, 0, stream>>>(obj, cnt);
  int nsb = (N_ENT + 255) / 256;  // 391
  k_scan1<<<nsb, 256, 0, stream>>>(cnt, cursor, blockSums);
  k_scan2<<<nsb, 256, 0, stream>>>(blockSums, rowStart, cursor);
  k_scatter<<<1024, 256, 0, stream>>>(subj, rel, obj, cursor, packed);

  float* cur = e_a;
  float* nxt = e_b;
  for (int t = 0; t < 3; t++) {
    k_step<<<BSZ, 320, 0, stream>>>(qwh, qemb, Wstep, bstep, Wcq, bcq, Wca, bca,
                                    Wrel, brel, last_c, rel_d, t);
    k_follow<<<2048, 256, 0, stream>>>(cur, rel_d, rowStart, packed, nxt,
                                       (t == 2) ? sums : nullptr);
    float* tmp = cur; cur = nxt; nxt = tmp;
  }

  k_predfeat<<<PF_NB, 256, 0, stream>>>(cur, sums, eemb, partials);
  k_reduce_pf<<<(DH * 64 + 255) / 256, 256, 0, stream>>>(partials, pf);
  k_hidden<<<(BSZ * D_CLS) / 256, 256, 0, stream>>>(pf, We1, be1, hiddenT);
  k_final<<<(N_ENT + 63) / 64, 256, 0, stream>>>(hiddenT, We2, be2, out);
}

// Round 11
// 1503.149 us; speedup vs baseline: 1.6023x; 1.6023x over previous
//
#include <hip/hip_runtime.h>
#include <cstdint>

#define BSZ   64
#define MAXQ  32
#define DH    300
#define N_ENT 100000
#define N_REL 18
#define N_TRI 600000
#define D_CLS 1024

// e_s [64][N_ENT] -> e_t [N_ENT][64]
__global__ __launch_bounds__(256) void k_transpose(const float* __restrict__ e_s,
                                                   float* __restrict__ e_t) {
  __shared__ float T[64][65];
  int e0 = blockIdx.x * 64;
  int lane = threadIdx.x & 63;
  int w = threadIdx.x >> 6;
  for (int b = w; b < 64; b += 4) {
    int e = e0 + lane;
    T[b][lane] = (e < N_ENT) ? e_s[b * N_ENT + e] : 0.f;
  }
  __syncthreads();
  for (int i = w; i < 64; i += 4) {
    int e = e0 + i;
    if (e < N_ENT) e_t[e * 64 + lane] = T[lane][i];
  }
}

// ---------- CSR-by-obj build (triples are launch-invariant; built once) ----------
__global__ __launch_bounds__(256) void k_hist(const int* __restrict__ obj,
                                              int* __restrict__ cnt) {
  int stride = gridDim.x * 256;
  for (int i = blockIdx.x * 256 + threadIdx.x; i < N_TRI; i += stride)
    atomicAdd(&cnt[obj[i]], 1);
}

// Per-block exclusive scan of cnt -> cursor(local), block totals -> blockSums
__global__ __launch_bounds__(256) void k_scan1(const int* __restrict__ cnt,
                                               int* __restrict__ cursor,
                                               int* __restrict__ blockSums) {
  __shared__ int sdata[256];
  int i = blockIdx.x * 256 + threadIdx.x;
  int v = (i < N_ENT) ? cnt[i] : 0;
  sdata[threadIdx.x] = v;
  __syncthreads();
  for (int off = 1; off < 256; off <<= 1) {
    int t = (threadIdx.x >= off) ? sdata[threadIdx.x - off] : 0;
    __syncthreads();
    sdata[threadIdx.x] += t;
    __syncthreads();
  }
  if (i < N_ENT) cursor[i] = sdata[threadIdx.x] - v;  // exclusive local scan
  if (threadIdx.x == 255) blockSums[blockIdx.x] = sdata[255];
}

// Add block offsets -> rowStart + cursor (scatter cursors)
__global__ __launch_bounds__(256) void k_scan2(const int* __restrict__ blockSums,
                                               int* __restrict__ rowStart,
                                               int* __restrict__ cursor) {
  __shared__ int offs;
  int b = blockIdx.x;
  if (threadIdx.x == 0) {
    int o = 0;
    for (int j = 0; j < b; j++) o += blockSums[j];
    offs = o;
  }
  __syncthreads();
  int i = b * 256 + threadIdx.x;
  if (i < N_ENT) {
    int v = cursor[i] + offs;
    rowStart[i] = v;
    cursor[i] = v;
  }
  if (i == 0) rowStart[N_ENT] = N_TRI;
}

// packed[pos] = subj | (rel << 17)   (subj < 2^17, rel < 32)
__global__ __launch_bounds__(256) void k_scatter(const int* __restrict__ subj,
                                                 const int* __restrict__ rel,
                                                 const int* __restrict__ obj,
                                                 int* __restrict__ cursor,
                                                 uint32_t* __restrict__ packed) {
  int stride = gridDim.x * 256;
  for (int i = blockIdx.x * 256 + threadIdx.x; i < N_TRI; i += stride) {
    int o = obj[i];
    int pos = atomicAdd(&cursor[o], 1);
    packed[pos] = (uint32_t)subj[i] | ((uint32_t)rel[i] << 17);
  }
}

// Fused per-step controller: q_t, cq_t, word attention softmax, last_c, rel_dist.
__global__ __launch_bounds__(320) void k_step(
    const float* __restrict__ qwh, const float* __restrict__ qemb,
    const float* __restrict__ Wstep, const float* __restrict__ bstep,
    const float* __restrict__ Wcq, const float* __restrict__ bcq,
    const float* __restrict__ Wca, const float* __restrict__ bca,
    const float* __restrict__ Wrel, const float* __restrict__ brel,
    float* __restrict__ last_c, float* __restrict__ rel_dist, int t) {
  int b = blockIdx.x;
  int tid = threadIdx.x;
  __shared__ float qe[DH], qtL[DH], lcL[DH], wcq[DH];
  __shared__ float lg[MAXQ], red[MAXQ * 8], dist[MAXQ];
  __shared__ float relL[N_REL];
  __shared__ float mx, sm;

  for (int j = tid; j < DH; j += 320) {
    qe[j] = qemb[b * DH + j];
    lcL[j] = last_c[b * DH + j];
  }
  __syncthreads();

  const float* Wt = Wstep + t * DH * DH;
  for (int j = tid; j < DH; j += 320) {
    float acc = bstep[t * DH + j];
    for (int k = 0; k < DH; k++) acc += qe[k] * Wt[k * DH + j];
    qtL[j] = tanhf(acc);
  }
  __syncthreads();

  for (int j = tid; j < DH; j += 320) {
    float acc = bcq[j];
    for (int k = 0; k < DH; k++) acc += lcL[k] * Wcq[k * DH + j];
    for (int k = 0; k < DH; k++) acc += qtL[k] * Wcq[(DH + k) * DH + j];
    wcq[j] = acc * Wca[j];
  }
  __syncthreads();

  if (tid < MAXQ * 8) {
    int q = tid >> 3, sub = tid & 7;
    const float* row = qwh + (b * MAXQ + q) * DH;
    float acc = 0.f;
    for (int d = sub; d < DH; d += 8) acc += wcq[d] * row[d];
    red[tid] = acc;
  }
  __syncthreads();
  if (tid < MAXQ) {
    float acc = bca[0];
    for (int s = 0; s < 8; s++) acc += red[tid * 8 + s];
    lg[tid] = acc;
  }
  __syncthreads();
  if (tid == 0) {
    float m = lg[0];
    for (int q = 1; q < MAXQ; q++) m = fmaxf(m, lg[q]);
    mx = m;
  }
  __syncthreads();
  if (tid < MAXQ) dist[tid] = expf(lg[tid] - mx);
  __syncthreads();
  if (tid == 0) {
    float s = 0.f;
    for (int q = 0; q < MAXQ; q++) s += dist[q];
    sm = s;
  }
  __syncthreads();

  for (int j = tid; j < DH; j += 320) {
    float acc = 0.f;
    for (int q = 0; q < MAXQ; q++) acc += dist[q] * qwh[(b * MAXQ + q) * DH + j];
    acc /= sm;
    lcL[j] = acc;
    last_c[b * DH + j] = acc;
  }
  __syncthreads();

  if (tid < N_REL) {
    float acc = brel[tid];
    for (int d = 0; d < DH; d++) acc += lcL[d] * Wrel[d * N_REL + tid];
    relL[tid] = acc;
  }
  __syncthreads();
  if (tid == 0) {
    float m = relL[0];
    for (int r = 1; r < N_REL; r++) m = fmaxf(m, relL[r]);
    mx = m;
  }
  __syncthreads();
  if (tid < N_REL) relL[tid] = expf(relL[tid] - mx);
  __syncthreads();
  if (tid == 0) {
    float s = 0.f;
    for (int r = 0; r < N_REL; r++) s += relL[r];
    sm = s;
  }
  __syncthreads();
  if (tid < N_REL) rel_dist[b * N_REL + tid] = relL[tid] / sm;
}

// follow (CSR, atomic-free): one wave per output entity, grid-stride.
// e_out[o*64+lane] = sum over row(o) of e_in[subj*64+lane] * relL[lane][rel]
// relL padded to stride 19 (gcd(19,32)=1 -> conflict-free LDS reads).
// Inner loop hand-unrolled x4: batch the independent gathers before the FMAs.
__global__ __launch_bounds__(256) void k_follow(
    const float* __restrict__ e_in, const float* __restrict__ rel_dist,
    const int* __restrict__ rowStart, const uint32_t* __restrict__ packed,
    float* __restrict__ e_out, float* __restrict__ sums) {
  __shared__ float relL[BSZ * 19];
  for (int i = threadIdx.x; i < BSZ * N_REL; i += 256) {
    int l = i / N_REL, r = i - l * N_REL;
    relL[l * 19 + r] = rel_dist[i];
  }
  __syncthreads();
  int lane = threadIdx.x & 63;
  int wave = (blockIdx.x << 2) | (threadIdx.x >> 6);
  int nwaves = gridDim.x << 2;
  const float* myrel = relL + lane * 19;
  float sacc = 0.f;
  for (int o = wave; o < N_ENT; o += nwaves) {
    int beg = rowStart[o], end = rowStart[o + 1];
    float acc = 0.f;
    int t = beg;
    for (; t + 4 <= end; t += 4) {
      uint32_t p0 = packed[t + 0];
      uint32_t p1 = packed[t + 1];
      uint32_t p2 = packed[t + 2];
      uint32_t p3 = packed[t + 3];
      float v0 = e_in[(p0 & 0x1FFFF) * 64 + lane];
      float v1 = e_in[(p1 & 0x1FFFF) * 64 + lane];
      float v2 = e_in[(p2 & 0x1FFFF) * 64 + lane];
      float v3 = e_in[(p3 & 0x1FFFF) * 64 + lane];
      acc += v0 * myrel[p0 >> 17];
      acc += v1 * myrel[p1 >> 17];
      acc += v2 * myrel[p2 >> 17];
      acc += v3 * myrel[p3 >> 17];
    }
    for (; t < end; ++t) {
      uint32_t p = packed[t];
      acc += e_in[(p & 0x1FFFF) * 64 + lane] * myrel[p >> 17];
    }
    e_out[(size_t)o * 64 + lane] = acc;
    sacc += acc;
  }
  if (sums) atomicAdd(&sums[lane], sacc);
}

#define PF_NB 512
#define PF_EPB 196
#define PF_CH 32
#define PF_RS 304   // padded row stride (floats), 76 float4
__global__ __launch_bounds__(256) void k_predfeat(
    const float* __restrict__ e, const float* __restrict__ sums,
    const float* __restrict__ ent_emb, float* __restrict__ partials) {
  __shared__ float embL[PF_CH * PF_RS];
  __shared__ float eL[PF_CH * 64];
  int tid = threadIdx.x;
  int b = tid & 63, g = tid >> 6;
  int e0 = blockIdx.x * PF_EPB;
  int e1 = e0 + PF_EPB;
  if (e1 > N_ENT) e1 = N_ENT;

  int sb = (4 * tid) & 63;
  float4 inv4 = make_float4(1.f / (sums[sb + 0] + 1e-6f), 1.f / (sums[sb + 1] + 1e-6f),
                            1.f / (sums[sb + 2] + 1e-6f), 1.f / (sums[sb + 3] + 1e-6f));

  float4 acc[19];
  #pragma unroll
  for (int k = 0; k < 19; k++) acc[k] = make_float4(0.f, 0.f, 0.f, 0.f);

  float4* embL4 = (float4*)embL;
  float4* eL4 = (float4*)eL;

  for (int ecur = e0; ecur < e1; ecur += PF_CH) {
    int n = min(PF_CH, e1 - ecur);
    __syncthreads();
    const float4* src = (const float4*)(ent_emb + (size_t)ecur * DH);
    for (int i = tid; i < n * 75; i += 256) {
      int ee = i / 75, j = i - ee * 75;
      embL4[ee * 76 + j] = src[i];
      if (j == 0) embL4[ee * 76 + 75] = make_float4(0.f, 0.f, 0.f, 0.f);
    }
    const float4* esrc = (const float4*)(e + (size_t)ecur * 64);
    for (int i = tid; i < n * 16; i += 256) {
      float4 v = esrc[i];
      v.x *= inv4.x; v.y *= inv4.y; v.z *= inv4.z; v.w *= inv4.w;
      eL4[i] = v;
    }
    __syncthreads();
    for (int ee = 0; ee < n; ee++) {
      float ev = eL[ee * 64 + b];
      const float4* em = embL4 + ee * 76 + g * 19;
      #pragma unroll
      for (int k = 0; k < 19; k++) {
        float4 m = em[k];
        acc[k].x += ev * m.x;
        acc[k].y += ev * m.y;
        acc[k].z += ev * m.z;
        acc[k].w += ev * m.w;
      }
    }
  }

  float* pout = partials + (size_t)blockIdx.x * (PF_RS * 64);
  #pragma unroll
  for (int k = 0; k < 19; k++) {
    int d = g * 76 + k * 4;
    pout[(d + 0) * 64 + b] = acc[k].x;
    pout[(d + 1) * 64 + b] = acc[k].y;
    pout[(d + 2) * 64 + b] = acc[k].z;
    pout[(d + 3) * 64 + b] = acc[k].w;
  }
}

__global__ __launch_bounds__(256) void k_reduce_pf(const float* __restrict__ partials,
                                                   float* __restrict__ pf) {
  int j = blockIdx.x * 256 + threadIdx.x;
  if (j >= DH * 64) return;
  int d = j >> 6, b = j & 63;
  float acc = 0.f;
  for (int c = 0; c < PF_NB; c++) acc += partials[(size_t)c * (PF_RS * 64) + j];
  pf[b * DH + d] = acc;
}

// hiddenT[j][b] = relu(pf[b,:] @ We1[:,j] + be1[j])
__global__ __launch_bounds__(256) void k_hidden(const float* __restrict__ pf,
                                                const float* __restrict__ We1,
                                                const float* __restrict__ be1,
                                                float* __restrict__ hiddenT) {
  int idx = blockIdx.x * 256 + threadIdx.x;
  int j = idx & (D_CLS - 1);
  int b = idx >> 10;
  float acc = be1[j];
  const float* p = pf + b * DH;
  for (int k = 0; k < DH; k++) acc += p[k] * We1[k * D_CLS + j];
  hiddenT[j * 64 + b] = fmaxf(acc, 0.f);
}

// out[b][o] = be2[o] for all b  (pre-init for the atomic split-K final GEMM)
__global__ __launch_bounds__(256) void k_init_out(const float* __restrict__ be2,
                                                  float* __restrict__ out) {
  int idx4 = blockIdx.x * 256 + threadIdx.x;      // float4 index
  int elem = idx4 * 4;                            // element index
  if (elem >= BSZ * N_ENT) return;
  int o = elem % N_ENT;                           // multiple of 4 (N_ENT%4==0)
  float4 bv = *(const float4*)(be2 + o);
  ((float4*)out)[idx4] = bv;
}

// Final GEMM — split-K across blockIdx.y (NOT across waves: wave-id-dependent
// pointers broke scalarization in v10, SGPR 112->32, vector-load storm).
// Block (x,y): 64 threads, o-stripe x (lane = column), k in [y*256,(y+1)*256).
// h = hT + y*256*64 is BLOCK-uniform -> s_load broadcast (v8 codegen: VGPR 64,
// SGPR 112). 1563*4 = 6252 waves (~6/SIMD) hides the s_load latency that
// capped v8 at 18% occupancy / 35% VALUBusy. We2 k-slices disjoint -> still
// read exactly once. Reduction: global atomicAdd into bias-pre-initialized out
// (round-4 evidence: these RMWs resolve in L2, WRITE_SIZE stays ~25 MB).
#define KF_SPLIT 4
#define KF_KC (D_CLS / KF_SPLIT)   // 256
__global__ __launch_bounds__(64) void k_final(const float* __restrict__ hT,
                                              const float* __restrict__ We2,
                                              float* __restrict__ out) {
  int o = blockIdx.x * 64 + threadIdx.x;
  bool valid = (o < N_ENT);
  int oc = valid ? o : 0;
  int k0 = blockIdx.y * KF_KC;

  float acc[64];
  #pragma unroll
  for (int b = 0; b < 64; b++) acc[b] = 0.f;

  const float* w = We2 + (size_t)k0 * N_ENT + oc;
  const float* h = hT + k0 * 64;               // block-uniform
  for (int kk = 0; kk < KF_KC; kk += 8) {
    float wv[8];
    #pragma unroll
    for (int u = 0; u < 8; u++) wv[u] = w[(size_t)(kk + u) * N_ENT];
    #pragma unroll
    for (int u = 0; u < 8; u++) {
      const float* hk = h + (kk + u) * 64;     // block-uniform -> s_load
      #pragma unroll
      for (int b = 0; b < 64; b++) acc[b] += hk[b] * wv[u];
    }
  }

  if (valid) {
    #pragma unroll
    for (int b = 0; b < 64; b++)
      atomicAdd(&out[(size_t)b * N_ENT + o], acc[b]);
  }
}

extern "C" void kernel_launch(void* const* d_in, const int* in_sizes, int n_in,
                              void* d_out, int out_size, void* d_ws, size_t ws_size,
                              hipStream_t stream) {
  const float* qwh   = (const float*)d_in[0];
  const float* qemb  = (const float*)d_in[1];
  const float* e_s   = (const float*)d_in[2];
  const float* Wstep = (const float*)d_in[3];
  const float* bstep = (const float*)d_in[4];
  const float* Wcq   = (const float*)d_in[5];
  const float* bcq   = (const float*)d_in[6];
  const float* Wca   = (const float*)d_in[7];
  const float* bca   = (const float*)d_in[8];
  const float* Wrel  = (const float*)d_in[9];
  const float* brel  = (const float*)d_in[10];
  const float* eemb  = (const float*)d_in[11];
  const float* We1   = (const float*)d_in[12];
  const float* be1   = (const float*)d_in[13];
  const float* We2   = (const float*)d_in[14];
  const float* be2   = (const float*)d_in[15];
  const int* subj    = (const int*)d_in[16];
  const int* rel     = (const int*)d_in[17];
  const int* obj     = (const int*)d_in[18];
  float* out = (float*)d_out;

  float* ws = (float*)d_ws;
  const size_t EB = (size_t)N_ENT * 64;            // 6,400,000 floats
  float* e_a      = ws;                             // ping
  float* e_b      = e_a + EB;                       // pong
  float* partials = e_b + EB;                       // 512*304*64 = 9,961,472
  float* last_c   = partials + (size_t)PF_NB * PF_RS * 64;  // 19,200
  float* sums     = last_c + BSZ * DH;              // 64
  float* rel_d    = sums + 64;                      // 1,152
  float* pf       = rel_d + BSZ * N_REL;            // 19,200
  float* hiddenT  = pf + BSZ * DH;                  // 65,536
  int* cnt        = (int*)(hiddenT + BSZ * D_CLS);  // 100,000
  int* rowStart   = cnt + N_ENT;                    // 100,001
  int* cursor     = rowStart + N_ENT + 1;           // 100,000
  int* blockSums  = cursor + N_ENT;                 // 391 (pad to 400)
  uint32_t* packed = (uint32_t*)(blockSums + 400);  // 600,000
  // total ~23.8M words ~95 MB

  // small zero-init: last_c + sums ; cnt histogram
  hipMemsetAsync(last_c, 0, (size_t)(BSZ * DH + 64) * sizeof(float), stream);
  hipMemsetAsync(cnt, 0, (size_t)N_ENT * sizeof(int), stream);

  k_transpose<<<(N_ENT + 63) / 64, 256, 0, stream>>>(e_s, e_a);

  // Build obj-CSR once (triples are step-invariant)
  k_hist<<<1024, 256, 0, stream>>>(obj, cnt);
  int nsb = (N_ENT + 255) / 256;  // 391
  k_scan1<<<nsb, 256, 0, stream>>>(cnt, cursor, blockSums);
  k_scan2<<<nsb, 256, 0, stream>>>(blockSums, rowStart, cursor);
  k_scatter<<<1024, 256, 0, stream>>>(subj, rel, obj, cursor, packed);

  float* cur = e_a;
  float* nxt = e_b;
  for (int t = 0; t < 3; t++) {
    k_step<<<BSZ, 320, 0, stream>>>(qwh, qemb, Wstep, bstep, Wcq, bcq, Wca, bca,
                                    Wrel, brel, last_c, rel_d, t);
    k_follow<<<2048, 256, 0, stream>>>(cur, rel_d, rowStart, packed, nxt,
                                       (t == 2) ? sums : nullptr);
    float* tmp = cur; cur = nxt; nxt = tmp;
  }

  k_predfeat<<<PF_NB, 256, 0, stream>>>(cur, sums, eemb, partials);
  k_reduce_pf<<<(DH * 64 + 255) / 256, 256, 0, stream>>>(partials, pf);
  k_hidden<<<(BSZ * D_CLS) / 256, 256, 0, stream>>>(pf, We1, be1, hiddenT);
  k_init_out<<<(BSZ * N_ENT / 4 + 255) / 256, 256, 0, stream>>>(be2, out);
  dim3 fgrid((N_ENT + 63) / 64, KF_SPLIT);
  k_final<<<fgrid, 64, 0, stream>>>(hiddenT, We2, out);
}